// Round 1
// baseline (585.651 us; speedup 1.0000x reference)
//
#include <hip/hip_runtime.h>

#define DM 128
#define NH 8
#define DHD 16
#define DFF 512
#define CLAMP_V 5.0f
#define LN_EPS 1e-5f

// ---------------- CSR build ----------------
__global__ void k_count(const int* __restrict__ dst, int* __restrict__ deg, int E) {
  int e = blockIdx.x * blockDim.x + threadIdx.x;
  if (e < E) atomicAdd(&deg[dst[e]], 1);
}

__global__ __launch_bounds__(1024) void k_scan(const int* __restrict__ deg,
                                               int* __restrict__ off, int n) {
  __shared__ int part[1024];
  int tid = threadIdx.x;
  int chunk = (n + 1023) >> 10;
  int b = tid * chunk, e = min(b + chunk, n);
  int s = 0;
  for (int i = b; i < e; ++i) s += deg[i];
  part[tid] = s;
  __syncthreads();
  for (int d = 1; d < 1024; d <<= 1) {
    int v = 0;
    if (tid >= d) v = part[tid - d];
    __syncthreads();
    part[tid] += v;
    __syncthreads();
  }
  int run = (tid == 0) ? 0 : part[tid - 1];
  for (int i = b; i < e; ++i) { off[i] = run; run += deg[i]; }
  if (tid == 1023) off[n] = run;
}

__global__ void k_scatter(const int* __restrict__ src, const int* __restrict__ dst,
                          const int* __restrict__ off, int* __restrict__ cur,
                          int* __restrict__ csr, int E) {
  int e = blockIdx.x * blockDim.x + threadIdx.x;
  if (e < E) {
    int d = dst[e];
    int p = off[d] + atomicAdd(&cur[d], 1);
    csr[p] = src[e];
  }
}

// ---------------- f32 tiled GEMM: C = act(A * W^T + bias) + res ----------------
// A: [M x K] row-major, W: [NO x K] row-major (so C[m,n] = dot(A[m,:], W[n,:]))
// flags: 1=bias, 2=relu, 4=residual-add(res, same shape as C)
#define BM 64
#define BN 64
#define BK 16
#define GPAD 4

__global__ __launch_bounds__(256) void k_gemm(
    const float* __restrict__ A, const float* __restrict__ W,
    const float* __restrict__ bias, const float* __restrict__ res,
    float* __restrict__ C, int M, int NO, int K, int flags)
{
  __shared__ __align__(16) float As[BK][BM + GPAD];
  __shared__ __align__(16) float Ws[BK][BN + GPAD];
  int bm = blockIdx.y * BM, bn = blockIdx.x * BN;
  int tid = threadIdx.x;
  int tm = (tid >> 4) << 2;
  int tn = (tid & 15) << 2;
  float acc[4][4] = {};
  for (int k0 = 0; k0 < K; k0 += BK) {
    #pragma unroll
    for (int i = tid; i < BM * BK; i += 256) {
      int m = i >> 4, k = i & (BK - 1);
      int gm = bm + m;
      As[k][m] = (gm < M) ? A[(size_t)gm * K + k0 + k] : 0.f;
    }
    #pragma unroll
    for (int i = tid; i < BN * BK; i += 256) {
      int n = i >> 4, k = i & (BK - 1);
      int gn = bn + n;
      Ws[k][n] = (gn < NO) ? W[(size_t)gn * K + k0 + k] : 0.f;
    }
    __syncthreads();
    #pragma unroll
    for (int k = 0; k < BK; ++k) {
      float4 av = *reinterpret_cast<const float4*>(&As[k][tm]);
      float4 bv = *reinterpret_cast<const float4*>(&Ws[k][tn]);
      float a[4] = {av.x, av.y, av.z, av.w};
      float b4[4] = {bv.x, bv.y, bv.z, bv.w};
      #pragma unroll
      for (int i = 0; i < 4; ++i)
        #pragma unroll
        for (int j = 0; j < 4; ++j)
          acc[i][j] = fmaf(a[i], b4[j], acc[i][j]);
    }
    __syncthreads();
  }
  #pragma unroll
  for (int i = 0; i < 4; ++i) {
    int gm = bm + tm + i;
    if (gm >= M) continue;
    #pragma unroll
    for (int j = 0; j < 4; ++j) {
      int gn = bn + tn + j;
      if (gn >= NO) continue;
      float v = acc[i][j];
      if (flags & 1) v += bias[gn];
      if (flags & 2) v = fmaxf(v, 0.f);
      if (flags & 4) v += res[(size_t)gm * NO + gn];
      C[(size_t)gm * NO + gn] = v;
    }
  }
}

// ---------------- per-node edge-softmax attention ----------------
// one wave (64 lanes) per destination node; lane holds dims {2l, 2l+1};
// head h = lane>>3 (dims 16h..16h+15 <-> lanes 8h..8h+7)
__global__ __launch_bounds__(256) void k_attn(
    const float* __restrict__ q, const float* __restrict__ k,
    const float* __restrict__ v, const int* __restrict__ off,
    const int* __restrict__ csr, float* __restrict__ out, int n)
{
  int node = blockIdx.x * 4 + (threadIdx.x >> 6);
  int lane = threadIdx.x & 63;
  if (node >= n) return;
  size_t base = (size_t)node * DM + 2 * lane;
  float q0 = q[base], q1 = q[base + 1];
  int b = off[node], e = off[node + 1];
  float m = -1e30f, s = 0.f, a0 = 0.f, a1 = 0.f;
  for (int i = b; i < e; ++i) {
    int sn = csr[i];
    size_t sb = (size_t)sn * DM + 2 * lane;
    float k0 = k[sb], k1 = k[sb + 1];
    float v0 = v[sb], v1 = v[sb + 1];
    float p = q0 * k0 + q1 * k1;
    p += __shfl_xor(p, 1);
    p += __shfl_xor(p, 2);
    p += __shfl_xor(p, 4);
    float u = p * 0.25f;   // 1/sqrt(DH=16)
    u = fminf(fmaxf(u, -CLAMP_V), CLAMP_V);
    float mn = fmaxf(m, u);
    float f = __expf(m - mn);   // exp(-inf)=0 on first edge
    float w = __expf(u - mn);
    s = s * f + w;
    a0 = a0 * f + w * v0;
    a1 = a1 * f + w * v1;
    m = mn;
  }
  float inv = (s > 0.f) ? 1.f / s : 0.f;   // empty segment -> 0 (matches reference)
  out[base] = a0 * inv;
  out[base + 1] = a1 * inv;
}

// ---------------- LayerNorm (wave per node, 128 dims) ----------------
__global__ __launch_bounds__(256) void k_ln(
    const float* __restrict__ x, const float* __restrict__ g,
    const float* __restrict__ b, float* __restrict__ out, int n)
{
  int node = blockIdx.x * 4 + (threadIdx.x >> 6);
  int lane = threadIdx.x & 63;
  if (node >= n) return;
  size_t base = (size_t)node * DM + 2 * lane;
  float x0 = x[base], x1 = x[base + 1];
  float sum = x0 + x1;
  #pragma unroll
  for (int msk = 1; msk < 64; msk <<= 1) sum += __shfl_xor(sum, msk);
  float mu = sum * (1.f / DM);
  float d0 = x0 - mu, d1 = x1 - mu;
  float vs = d0 * d0 + d1 * d1;
  #pragma unroll
  for (int msk = 1; msk < 64; msk <<= 1) vs += __shfl_xor(vs, msk);
  float rstd = rsqrtf(vs * (1.f / DM) + LN_EPS);
  out[base]     = d0 * rstd * g[2 * lane]     + b[2 * lane];
  out[base + 1] = d1 * rstd * g[2 * lane + 1] + b[2 * lane + 1];
}

extern "C" void kernel_launch(void* const* d_in, const int* in_sizes, int n_in,
                              void* d_out, int out_size, void* d_ws, size_t ws_size,
                              hipStream_t stream)
{
  const float* feat = (const float*)d_in[0];
  const int*   src  = (const int*)d_in[1];
  const int*   dst  = (const int*)d_in[2];
  const float* Wq   = (const float*)d_in[3];
  const float* Wk   = (const float*)d_in[4];
  const float* Wv   = (const float*)d_in[5];
  const float* Wo   = (const float*)d_in[6];
  const float* ln1g = (const float*)d_in[7];
  const float* ln1b = (const float*)d_in[8];
  const float* W1   = (const float*)d_in[9];
  const float* b1   = (const float*)d_in[10];
  const float* W2   = (const float*)d_in[11];
  const float* b2   = (const float*)d_in[12];
  const float* ln2g = (const float*)d_in[13];
  const float* ln2b = (const float*)d_in[14];
  float* out = (float*)d_out;

  int N = in_sizes[0] / DM;
  int E = in_sizes[1];
  size_t NF = (size_t)N * DM;

  // workspace layout (floats): q | k | v | sum_av | x1 | h1 ; mid aliases q..sum_av (N*512), x2 aliases x1
  float* ws  = (float*)d_ws;
  float* q   = ws;
  float* kk  = ws + NF;
  float* vv  = ws + 2 * NF;
  float* sav = ws + 3 * NF;
  float* x1  = ws + 4 * NF;
  float* h1  = ws + 5 * NF;
  float* mid = ws;        // N*DFF = 4*NF floats, q/k/v/sum_av dead by then
  float* x2  = x1;        // x1 dead after ln1
  int* ib  = (int*)(ws + 6 * NF);
  int* deg = ib;
  int* cur = ib + N;
  int* off = ib + 2 * N;
  int* csr = ib + 3 * N + 1;

  hipMemsetAsync(deg, 0, 2 * (size_t)N * sizeof(int), stream);
  int eb = (E + 255) / 256;
  k_count<<<eb, 256, 0, stream>>>(dst, deg, E);
  k_scan<<<1, 1024, 0, stream>>>(deg, off, N);
  k_scatter<<<eb, 256, 0, stream>>>(src, dst, off, cur, csr, E);

  int gy = (N + BM - 1) / BM;
  // q,k,v projections
  k_gemm<<<dim3(DM / BN, gy), 256, 0, stream>>>(feat, Wq, nullptr, nullptr, q,  N, DM, DM, 0);
  k_gemm<<<dim3(DM / BN, gy), 256, 0, stream>>>(feat, Wk, nullptr, nullptr, kk, N, DM, DM, 0);
  k_gemm<<<dim3(DM / BN, gy), 256, 0, stream>>>(feat, Wv, nullptr, nullptr, vv, N, DM, DM, 0);

  int nb4 = (N + 3) / 4;
  k_attn<<<nb4, 256, 0, stream>>>(q, kk, vv, off, csr, sav, N);

  // x1 = sum_av @ Wo^T + feat
  k_gemm<<<dim3(DM / BN, gy), 256, 0, stream>>>(sav, Wo, nullptr, feat, x1, N, DM, DM, 4);
  k_ln<<<nb4, 256, 0, stream>>>(x1, ln1g, ln1b, h1, N);
  // mid = relu(h1 @ W1^T + b1)
  k_gemm<<<dim3(DFF / BN, gy), 256, 0, stream>>>(h1, W1, b1, nullptr, mid, N, DFF, DM, 3);
  // x2 = mid @ W2^T + b2 + h1
  k_gemm<<<dim3(DM / BN, gy), 256, 0, stream>>>(mid, W2, b2, h1, x2, N, DM, DFF, 5);
  k_ln<<<nb4, 256, 0, stream>>>(x2, ln2g, ln2b, out, N);
}

// Round 2
// 328.651 us; speedup vs baseline: 1.7820x; 1.7820x over previous
//
#include <hip/hip_runtime.h>

#define DM 128
#define DFF 512
#define CLAMP_V 5.0f
#define LN_EPS 1e-5f

typedef __attribute__((ext_vector_type(8))) short bf16x8;
typedef __attribute__((ext_vector_type(4))) float f32x4;

__device__ __forceinline__ float b2f(ushort u) {
  union { uint u; float f; } x; x.u = ((uint)u) << 16; return x.f;
}
__device__ __forceinline__ ushort f2b(float f) {
  union { float f; uint u; } x; x.f = f;
  uint r = x.u + 0x7FFFu + ((x.u >> 16) & 1u);
  return (ushort)(r >> 16);
}

// ---------------- casts ----------------
__global__ void k_cast(const float* __restrict__ s, ushort* __restrict__ d, int n) {
  int i4 = (blockIdx.x * blockDim.x + threadIdx.x) * 4;
  if (i4 + 3 < n) {
    float4 v = *reinterpret_cast<const float4*>(s + i4);
    ushort4 o; o.x = f2b(v.x); o.y = f2b(v.y); o.z = f2b(v.z); o.w = f2b(v.w);
    *reinterpret_cast<ushort4*>(d + i4) = o;
  } else {
    for (; i4 < n; ++i4) d[i4] = f2b(s[i4]);
  }
}

// all weights -> one contiguous bf16 buffer: wqkv(3*16384) | wo(16384) | w1(65536) | w2(65536)
__global__ void k_castw(const float* __restrict__ wq, const float* __restrict__ wk,
                        const float* __restrict__ wv, const float* __restrict__ wo,
                        const float* __restrict__ w1, const float* __restrict__ w2,
                        ushort* __restrict__ d) {
  int i4 = (blockIdx.x * blockDim.x + threadIdx.x) * 4;
  if (i4 >= 196608) return;
  const float* s; int o;
  if      (i4 < 16384)  { s = wq; o = i4; }
  else if (i4 < 32768)  { s = wk; o = i4 - 16384; }
  else if (i4 < 49152)  { s = wv; o = i4 - 32768; }
  else if (i4 < 65536)  { s = wo; o = i4 - 49152; }
  else if (i4 < 131072) { s = w1; o = i4 - 65536; }
  else                  { s = w2; o = i4 - 131072; }
  float4 v = *reinterpret_cast<const float4*>(s + o);
  ushort4 u; u.x = f2b(v.x); u.y = f2b(v.y); u.z = f2b(v.z); u.w = f2b(v.w);
  *reinterpret_cast<ushort4*>(d + i4) = u;
}

// ---------------- CSR build ----------------
__global__ void k_count(const int* __restrict__ dst, int* __restrict__ deg, int E) {
  int e = blockIdx.x * blockDim.x + threadIdx.x;
  if (e < E) atomicAdd(&deg[dst[e]], 1);
}

__global__ __launch_bounds__(1024) void k_scan(const int* __restrict__ deg,
                                               int* __restrict__ off, int n) {
  __shared__ int part[1024];
  int tid = threadIdx.x;
  int chunk = (n + 1023) >> 10;
  int b = tid * chunk, e = min(b + chunk, n);
  int s = 0;
  for (int i = b; i < e; ++i) s += deg[i];
  part[tid] = s;
  __syncthreads();
  for (int d = 1; d < 1024; d <<= 1) {
    int v = 0;
    if (tid >= d) v = part[tid - d];
    __syncthreads();
    part[tid] += v;
    __syncthreads();
  }
  int run = (tid == 0) ? 0 : part[tid - 1];
  for (int i = b; i < e; ++i) { off[i] = run; run += deg[i]; }
  if (tid == 1023) off[n] = run;
}

__global__ void k_scatter(const int* __restrict__ src, const int* __restrict__ dst,
                          const int* __restrict__ off, int* __restrict__ cur,
                          int* __restrict__ csr, int E) {
  int e = blockIdx.x * blockDim.x + threadIdx.x;
  if (e < E) {
    int d = dst[e];
    int p = off[d] + atomicAdd(&cur[d], 1);
    csr[p] = src[e];
  }
}

// ---------------- bf16 MFMA GEMM: C = act(A * W^T + bias) (+ res) ----------------
// A: [M x K] bf16 row-major, W: [NO x K] bf16 row-major, NO % 128 == 0, K % 64 == 0
// 128x128 tile, BK=64, 4 waves (2x2), each wave 64x64 = 4x4 frags of 16x16x32.
// LDS: linear dest for global_load_lds; XOR-swizzle (chunk ^= row&7) applied on the
// *source* address at stage time and on the ds_read address (both-sides, rule #21).
#define BM 128
#define BN 128
#define BK 64

template<int FLAGS, bool OUTF, bool OUTB>
__global__ __launch_bounds__(256, 2) void k_mm(
    const ushort* __restrict__ A, const ushort* __restrict__ W,
    const float* __restrict__ bias, const float* __restrict__ res,
    float* __restrict__ Cf, ushort* __restrict__ Cb,
    int M, int NO, int K)
{
  __shared__ ushort As[BM * BK];
  __shared__ ushort Ws[BN * BK];
  const int tid = threadIdx.x;
  const int wv = tid >> 6, ln = tid & 63;
  const int bm = blockIdx.y * BM, bn = blockIdx.x * BN;
  const int wrow = (wv >> 1) * 64, wcol = (wv & 1) * 64;

  f32x4 acc[4][4] = {};

  // staging geometry: per issue, 256 threads x 16B = 4KB; 4 issues per 16KB tile.
  // linear LDS byte offset o = is*4096 + wv*1024 + ln*16 ; row = o>>7 (128B rows),
  // physical chunk p = (o>>4)&7 ; logical k-chunk staged there = p ^ (row&7).
  const int o_base = wv * 1024 + ln * 16;

  for (int k0 = 0; k0 < K; k0 += BK) {
    #pragma unroll
    for (int is = 0; is < 4; ++is) {
      int o = is * 4096 + o_base;
      int row = o >> 7;
      int c = ((o >> 4) & 7) ^ (row & 7);
      int gm = bm + row; if (gm >= M) gm = M - 1;
      const ushort* srcA = A + (size_t)gm * K + k0 + c * 8;
      __builtin_amdgcn_global_load_lds(
          (const __attribute__((address_space(1))) void*)srcA,
          (__attribute__((address_space(3))) void*)((char*)As + is * 4096 + wv * 1024),
          16, 0, 0);
      int gn = bn + row;  // NO % 128 == 0 -> always in range
      const ushort* srcW = W + (size_t)gn * K + k0 + c * 8;
      __builtin_amdgcn_global_load_lds(
          (const __attribute__((address_space(1))) void*)srcW,
          (__attribute__((address_space(3))) void*)((char*)Ws + is * 4096 + wv * 1024),
          16, 0, 0);
    }
    __syncthreads();

    const char* AsB = (const char*)As;
    const char* WsB = (const char*)Ws;
    #pragma unroll
    for (int kk = 0; kk < 2; ++kk) {
      bf16x8 af[4], bf[4];
      #pragma unroll
      for (int m = 0; m < 4; ++m) {
        int r = wrow + m * 16 + (ln & 15);
        int c = kk * 4 + (ln >> 4);
        af[m] = *reinterpret_cast<const bf16x8*>(AsB + r * 128 + ((c ^ (r & 7)) << 4));
      }
      #pragma unroll
      for (int n = 0; n < 4; ++n) {
        int r = wcol + n * 16 + (ln & 15);
        int c = kk * 4 + (ln >> 4);
        bf[n] = *reinterpret_cast<const bf16x8*>(WsB + r * 128 + ((c ^ (r & 7)) << 4));
      }
      #pragma unroll
      for (int m = 0; m < 4; ++m)
        #pragma unroll
        for (int n = 0; n < 4; ++n)
          acc[m][n] = __builtin_amdgcn_mfma_f32_16x16x32_bf16(af[m], bf[n], acc[m][n], 0, 0, 0);
    }
    __syncthreads();
  }

  // epilogue: C/D layout col = lane&15, row = (lane>>4)*4 + reg
  #pragma unroll
  for (int m = 0; m < 4; ++m) {
    int gr0 = bm + wrow + m * 16 + (ln >> 4) * 4;
    #pragma unroll
    for (int n = 0; n < 4; ++n) {
      int gc = bn + wcol + n * 16 + (ln & 15);
      float bsv = (FLAGS & 1) ? bias[gc] : 0.f;
      #pragma unroll
      for (int r = 0; r < 4; ++r) {
        int gr = gr0 + r;
        if (gr >= M) continue;
        float v = acc[m][n][r] + bsv;
        if (FLAGS & 2) v = fmaxf(v, 0.f);
        if (FLAGS & 4) v += res[(size_t)gr * NO + gc];
        if (OUTF) Cf[(size_t)gr * NO + gc] = v;
        if (OUTB) Cb[(size_t)gr * NO + gc] = f2b(v);
      }
    }
  }
}

// ---------------- per-node edge-softmax attention (bf16 qkv, row stride 384) ----------------
__global__ __launch_bounds__(256) void k_attn(
    const ushort* __restrict__ qkv, const int* __restrict__ off,
    const int* __restrict__ csr, ushort* __restrict__ sav, int n)
{
  int node = blockIdx.x * 4 + (threadIdx.x >> 6);
  int lane = threadIdx.x & 63;
  if (node >= n) return;
  const ushort* qr = qkv + (size_t)node * 384 + 2 * lane;
  float q0 = b2f(qr[0]), q1 = b2f(qr[1]);
  int b = off[node], e = off[node + 1];
  float m = -1e30f, s = 0.f, a0 = 0.f, a1 = 0.f;
  for (int i = b; i < e; ++i) {
    int sn = csr[i];
    const ushort* kr = qkv + (size_t)sn * 384 + 128 + 2 * lane;
    uint kw = *reinterpret_cast<const uint*>(kr);
    uint vw = *reinterpret_cast<const uint*>(kr + 128);
    float p = q0 * b2f((ushort)kw) + q1 * b2f((ushort)(kw >> 16));
    p += __shfl_xor(p, 1);
    p += __shfl_xor(p, 2);
    p += __shfl_xor(p, 4);
    float u = p * 0.25f;  // 1/sqrt(16)
    u = fminf(fmaxf(u, -CLAMP_V), CLAMP_V);
    float mn = fmaxf(m, u);
    float f = __expf(m - mn);
    float w = __expf(u - mn);
    s = s * f + w;
    a0 = a0 * f + w * b2f((ushort)vw);
    a1 = a1 * f + w * b2f((ushort)(vw >> 16));
    m = mn;
  }
  float inv = (s > 0.f) ? 1.f / s : 0.f;
  ushort2 o; o.x = f2b(a0 * inv); o.y = f2b(a1 * inv);
  *reinterpret_cast<ushort2*>(sav + (size_t)node * DM + 2 * lane) = o;
}

// ---------------- LayerNorm (wave per node); optional bf16 second output ----------------
__global__ __launch_bounds__(256) void k_ln(
    const float* __restrict__ x, const float* __restrict__ g,
    const float* __restrict__ b, float* __restrict__ outf,
    ushort* __restrict__ outb, int n)
{
  int node = blockIdx.x * 4 + (threadIdx.x >> 6);
  int lane = threadIdx.x & 63;
  if (node >= n) return;
  size_t base = (size_t)node * DM + 2 * lane;
  float x0 = x[base], x1 = x[base + 1];
  float sum = x0 + x1;
  #pragma unroll
  for (int msk = 1; msk < 64; msk <<= 1) sum += __shfl_xor(sum, msk);
  float mu = sum * (1.f / DM);
  float d0 = x0 - mu, d1 = x1 - mu;
  float vs = d0 * d0 + d1 * d1;
  #pragma unroll
  for (int msk = 1; msk < 64; msk <<= 1) vs += __shfl_xor(vs, msk);
  float rstd = rsqrtf(vs * (1.f / DM) + LN_EPS);
  float y0 = d0 * rstd * g[2 * lane]     + b[2 * lane];
  float y1 = d1 * rstd * g[2 * lane + 1] + b[2 * lane + 1];
  outf[base]     = y0;
  outf[base + 1] = y1;
  if (outb) {
    ushort2 o; o.x = f2b(y0); o.y = f2b(y1);
    *reinterpret_cast<ushort2*>(outb + base) = o;
  }
}

extern "C" void kernel_launch(void* const* d_in, const int* in_sizes, int n_in,
                              void* d_out, int out_size, void* d_ws, size_t ws_size,
                              hipStream_t stream)
{
  const float* feat = (const float*)d_in[0];
  const int*   src  = (const int*)d_in[1];
  const int*   dst  = (const int*)d_in[2];
  const float* Wq   = (const float*)d_in[3];
  const float* Wk   = (const float*)d_in[4];
  const float* Wv   = (const float*)d_in[5];
  const float* Wo   = (const float*)d_in[6];
  const float* ln1g = (const float*)d_in[7];
  const float* ln1b = (const float*)d_in[8];
  const float* W1   = (const float*)d_in[9];
  const float* b1   = (const float*)d_in[10];
  const float* W2   = (const float*)d_in[11];
  const float* b2   = (const float*)d_in[12];
  const float* ln2g = (const float*)d_in[13];
  const float* ln2b = (const float*)d_in[14];
  float* out = (float*)d_out;

  const int N = in_sizes[0] / DM;
  const int E = in_sizes[1];
  const size_t NB = (size_t)N;

  // workspace layout (bytes):
  // [0, N*768)              qkv_bf  (N x 384 bf16)   } mid_bf (N x 512 bf16) aliases
  // [N*768, N*1024)         feat_bf (N x 128 bf16)   }   [0, N*1024) after attn+wo
  // [N*1024, +N*512)        x1 f32  (x2 aliases)
  // [+N*512)                h1 f32
  // [+N*256)                h1_bf
  // [+393216)               weights bf16: wqkv|wo|w1|w2
  // then ints: deg N | cur N | off N+1 | csr E
  char* wsb = (char*)d_ws;
  ushort* qkv_bf  = (ushort*)wsb;
  ushort* feat_bf = (ushort*)(wsb + NB * 768);
  ushort* sav_bf  = feat_bf;
  ushort* mid_bf  = (ushort*)wsb;
  float*  x1      = (float*)(wsb + NB * 1024);
  float*  h1      = (float*)(wsb + NB * 1024 + NB * 512);
  ushort* h1b     = (ushort*)(wsb + NB * 1024 + NB * 1024);
  ushort* wbf     = (ushort*)(wsb + NB * 1024 + NB * 1024 + NB * 256);
  ushort* wqkv_bf = wbf;
  ushort* wo_bf   = wbf + 49152;
  ushort* w1_bf   = wbf + 65536;
  ushort* w2_bf   = wbf + 131072;
  int* ib  = (int*)(wbf + 196608);
  int* deg = ib;
  int* cur = ib + N;
  int* off = ib + 2 * N;
  int* csr = ib + 3 * N + 1;

  hipMemsetAsync(deg, 0, 2 * (size_t)N * sizeof(int), stream);

  // casts
  int nf = N * DM;
  k_cast<<<(nf / 4 + 255) / 256, 256, 0, stream>>>(feat, feat_bf, nf);
  k_castw<<<192, 256, 0, stream>>>(Wq, Wk, Wv, Wo, W1, W2, wbf);

  // CSR
  int eb = (E + 255) / 256;
  k_count<<<eb, 256, 0, stream>>>(dst, deg, E);
  k_scan<<<1, 1024, 0, stream>>>(deg, off, N);
  k_scatter<<<eb, 256, 0, stream>>>(src, dst, off, cur, csr, E);

  const int gy = (N + BM - 1) / BM;
  // qkv = feat @ Wqkv^T   [N x 384] bf16
  k_mm<0, false, true><<<dim3(3, gy), 256, 0, stream>>>(
      feat_bf, wqkv_bf, nullptr, nullptr, nullptr, qkv_bf, N, 384, DM);

  int nb4 = (N + 3) / 4;
  k_attn<<<nb4, 256, 0, stream>>>(qkv_bf, off, csr, sav_bf, N);

  // x1 = sav @ Wo^T + feat   [N x 128] f32
  k_mm<4, true, false><<<dim3(1, gy), 256, 0, stream>>>(
      sav_bf, wo_bf, nullptr, feat, x1, nullptr, N, DM, DM);
  k_ln<<<nb4, 256, 0, stream>>>(x1, ln1g, ln1b, h1, h1b, N);

  // mid = relu(h1 @ W1^T + b1)   [N x 512] bf16
  k_mm<3, false, true><<<dim3(4, gy), 256, 0, stream>>>(
      h1b, w1_bf, b1, nullptr, nullptr, mid_bf, N, DFF, DM);
  // x2 = mid @ W2^T + b2 + h1   [N x 128] f32  (x2 aliases x1)
  k_mm<5, true, false><<<dim3(1, gy), 256, 0, stream>>>(
      mid_bf, w2_bf, b2, h1, x1, nullptr, N, DM, DFF);

  k_ln<<<nb4, 256, 0, stream>>>(x1, ln2g, ln2b, out, nullptr, N);
}

// Round 3
// 292.158 us; speedup vs baseline: 2.0046x; 1.1249x over previous
//
#include <hip/hip_runtime.h>

#define DM 128
#define DFF 512
#define CLAMP_V 5.0f
#define LN_EPS 1e-5f

typedef __attribute__((ext_vector_type(8))) short bf16x8;
typedef __attribute__((ext_vector_type(4))) float f32x4;

__device__ __forceinline__ float b2f(ushort u) {
  union { uint u; float f; } x; x.u = ((uint)u) << 16; return x.f;
}
__device__ __forceinline__ ushort f2b(float f) {
  union { float f; uint u; } x; x.f = f;
  uint r = x.u + 0x7FFFu + ((x.u >> 16) & 1u);
  return (ushort)(r >> 16);
}
__device__ __forceinline__ void unpack8(uint4 w, float* o) {
  o[0] = b2f((ushort)w.x); o[1] = b2f((ushort)(w.x >> 16));
  o[2] = b2f((ushort)w.y); o[3] = b2f((ushort)(w.y >> 16));
  o[4] = b2f((ushort)w.z); o[5] = b2f((ushort)(w.z >> 16));
  o[6] = b2f((ushort)w.w); o[7] = b2f((ushort)(w.w >> 16));
}

// ---------------- casts ----------------
__global__ void k_cast(const float* __restrict__ s, ushort* __restrict__ d, int n) {
  int i4 = (blockIdx.x * blockDim.x + threadIdx.x) * 4;
  if (i4 + 3 < n) {
    float4 v = *reinterpret_cast<const float4*>(s + i4);
    ushort4 o; o.x = f2b(v.x); o.y = f2b(v.y); o.z = f2b(v.z); o.w = f2b(v.w);
    *reinterpret_cast<ushort4*>(d + i4) = o;
  } else {
    for (; i4 < n; ++i4) d[i4] = f2b(s[i4]);
  }
}

// all weights -> one contiguous bf16 buffer: wqkv(3*16384) | wo(16384) | w1(65536) | w2(65536)
__global__ void k_castw(const float* __restrict__ wq, const float* __restrict__ wk,
                        const float* __restrict__ wv, const float* __restrict__ wo,
                        const float* __restrict__ w1, const float* __restrict__ w2,
                        ushort* __restrict__ d) {
  int i4 = (blockIdx.x * blockDim.x + threadIdx.x) * 4;
  if (i4 >= 196608) return;
  const float* s; int o;
  if      (i4 < 16384)  { s = wq; o = i4; }
  else if (i4 < 32768)  { s = wk; o = i4 - 16384; }
  else if (i4 < 49152)  { s = wv; o = i4 - 32768; }
  else if (i4 < 65536)  { s = wo; o = i4 - 49152; }
  else if (i4 < 131072) { s = w1; o = i4 - 65536; }
  else                  { s = w2; o = i4 - 131072; }
  float4 v = *reinterpret_cast<const float4*>(s + o);
  ushort4 u; u.x = f2b(v.x); u.y = f2b(v.y); u.z = f2b(v.z); u.w = f2b(v.w);
  *reinterpret_cast<ushort4*>(d + i4) = u;
}

// ---------------- CSR build ----------------
__global__ void k_count(const int* __restrict__ dst, int* __restrict__ deg, int E) {
  int e = blockIdx.x * blockDim.x + threadIdx.x;
  if (e < E) atomicAdd(&deg[dst[e]], 1);
}

__global__ __launch_bounds__(1024) void k_scan(const int* __restrict__ deg,
                                               int* __restrict__ off, int n) {
  __shared__ int part[1024];
  int tid = threadIdx.x;
  int chunk = (n + 1023) >> 10;
  int b = tid * chunk, e = min(b + chunk, n);
  int s = 0;
  for (int i = b; i < e; ++i) s += deg[i];
  part[tid] = s;
  __syncthreads();
  for (int d = 1; d < 1024; d <<= 1) {
    int v = 0;
    if (tid >= d) v = part[tid - d];
    __syncthreads();
    part[tid] += v;
    __syncthreads();
  }
  int run = (tid == 0) ? 0 : part[tid - 1];
  for (int i = b; i < e; ++i) { off[i] = run; run += deg[i]; }
  if (tid == 1023) off[n] = run;
}

__global__ void k_scatter(const int* __restrict__ src, const int* __restrict__ dst,
                          const int* __restrict__ off, int* __restrict__ cur,
                          int* __restrict__ csr, int E) {
  int e = blockIdx.x * blockDim.x + threadIdx.x;
  if (e < E) {
    int d = dst[e];
    int p = off[d] + atomicAdd(&cur[d], 1);
    csr[p] = src[e];
  }
}

// ---------------- bf16 MFMA GEMM (unchanged from round 2) ----------------
#define BM 128
#define BN 128
#define BK 64

template<int FLAGS, bool OUTF, bool OUTB>
__global__ __launch_bounds__(256, 2) void k_mm(
    const ushort* __restrict__ A, const ushort* __restrict__ W,
    const float* __restrict__ bias, const float* __restrict__ res,
    float* __restrict__ Cf, ushort* __restrict__ Cb,
    int M, int NO, int K)
{
  __shared__ ushort As[BM * BK];
  __shared__ ushort Ws[BN * BK];
  const int tid = threadIdx.x;
  const int wv = tid >> 6, ln = tid & 63;
  const int bm = blockIdx.y * BM, bn = blockIdx.x * BN;
  const int wrow = (wv >> 1) * 64, wcol = (wv & 1) * 64;

  f32x4 acc[4][4] = {};
  const int o_base = wv * 1024 + ln * 16;

  for (int k0 = 0; k0 < K; k0 += BK) {
    #pragma unroll
    for (int is = 0; is < 4; ++is) {
      int o = is * 4096 + o_base;
      int row = o >> 7;
      int c = ((o >> 4) & 7) ^ (row & 7);
      int gm = bm + row; if (gm >= M) gm = M - 1;
      const ushort* srcA = A + (size_t)gm * K + k0 + c * 8;
      __builtin_amdgcn_global_load_lds(
          (const __attribute__((address_space(1))) void*)srcA,
          (__attribute__((address_space(3))) void*)((char*)As + is * 4096 + wv * 1024),
          16, 0, 0);
      int gn = bn + row;
      const ushort* srcW = W + (size_t)gn * K + k0 + c * 8;
      __builtin_amdgcn_global_load_lds(
          (const __attribute__((address_space(1))) void*)srcW,
          (__attribute__((address_space(3))) void*)((char*)Ws + is * 4096 + wv * 1024),
          16, 0, 0);
    }
    __syncthreads();

    const char* AsB = (const char*)As;
    const char* WsB = (const char*)Ws;
    #pragma unroll
    for (int kk = 0; kk < 2; ++kk) {
      bf16x8 af[4], bf[4];
      #pragma unroll
      for (int m = 0; m < 4; ++m) {
        int r = wrow + m * 16 + (ln & 15);
        int c = kk * 4 + (ln >> 4);
        af[m] = *reinterpret_cast<const bf16x8*>(AsB + r * 128 + ((c ^ (r & 7)) << 4));
      }
      #pragma unroll
      for (int n = 0; n < 4; ++n) {
        int r = wcol + n * 16 + (ln & 15);
        int c = kk * 4 + (ln >> 4);
        bf[n] = *reinterpret_cast<const bf16x8*>(WsB + r * 128 + ((c ^ (r & 7)) << 4));
      }
      #pragma unroll
      for (int m = 0; m < 4; ++m)
        #pragma unroll
        for (int n = 0; n < 4; ++n)
          acc[m][n] = __builtin_amdgcn_mfma_f32_16x16x32_bf16(af[m], bf[n], acc[m][n], 0, 0, 0);
    }
    __syncthreads();
  }

  #pragma unroll
  for (int m = 0; m < 4; ++m) {
    int gr0 = bm + wrow + m * 16 + (ln >> 4) * 4;
    #pragma unroll
    for (int n = 0; n < 4; ++n) {
      int gc = bn + wcol + n * 16 + (ln & 15);
      float bsv = (FLAGS & 1) ? bias[gc] : 0.f;
      #pragma unroll
      for (int r = 0; r < 4; ++r) {
        int gr = gr0 + r;
        if (gr >= M) continue;
        float v = acc[m][n][r] + bsv;
        if (FLAGS & 2) v = fmaxf(v, 0.f);
        if (FLAGS & 4) v += res[(size_t)gr * NO + gc];
        if (OUTF) Cf[(size_t)gr * NO + gc] = v;
        if (OUTB) Cb[(size_t)gr * NO + gc] = f2b(v);
      }
    }
  }
}

// ---------------- per-node edge-softmax attention, 4 edges in flight per wave ----
// wave = 4 groups x 16 lanes; group g handles edges b+4i+g; lane holds dims
// [sl*8, sl*8+8) (sl = lane&15), head = sl>>1. Per-group online softmax partials
// merged at the end via shfl_xor(16/32) max-rescale combine.
__global__ __launch_bounds__(256) void k_attn(
    const ushort* __restrict__ qkv, const int* __restrict__ off,
    const int* __restrict__ csr, ushort* __restrict__ sav, int n)
{
  int node = blockIdx.x * 4 + (threadIdx.x >> 6);
  int lane = threadIdx.x & 63;
  if (node >= n) return;
  const int g = lane >> 4, sl = lane & 15;

  uint4 qw = *reinterpret_cast<const uint4*>(qkv + (size_t)node * 384 + sl * 8);
  float qv[8]; unpack8(qw, qv);

  int b = off[node], e = off[node + 1];
  float m = -1e30f, s = 0.f;
  float a[8] = {};
  int nIt = (e - b + 3) >> 2;
  int idx = b + g;
  int sn = (b < e) ? csr[min(idx, e - 1)] : 0;

  for (int i = 0; i < nIt; ++i) {
    bool act = idx < e;
    const ushort* kr = qkv + (size_t)sn * 384 + 128 + sl * 8;
    uint4 kw = *reinterpret_cast<const uint4*>(kr);
    uint4 vw = *reinterpret_cast<const uint4*>(kr + 128);
    int idxn = idx + 4;
    if (i + 1 < nIt) sn = csr[min(idxn, e - 1)];   // prefetch next edge id
    idx = idxn;

    float kv[8]; unpack8(kw, kv);
    float p = 0.f;
    #pragma unroll
    for (int j = 0; j < 8; ++j) p = fmaf(qv[j], kv[j], p);
    p += __shfl_xor(p, 1);                          // head pair (16 dims)
    float u = fminf(fmaxf(p * 0.25f, -CLAMP_V), CLAMP_V);
    if (act) {
      float mn = fmaxf(m, u);
      float f = __expf(m - mn);
      float w = __expf(u - mn);
      s = s * f + w;
      float vv[8]; unpack8(vw, vv);
      #pragma unroll
      for (int j = 0; j < 8; ++j) a[j] = a[j] * f + w * vv[j];
      m = mn;
    }
  }

  // merge the 4 group partials (butterfly over lane bits 4,5)
  #pragma unroll
  for (int msk = 16; msk <= 32; msk <<= 1) {
    float mo = __shfl_xor(m, msk);
    float so = __shfl_xor(s, msk);
    float ao[8];
    #pragma unroll
    for (int j = 0; j < 8; ++j) ao[j] = __shfl_xor(a[j], msk);
    float mn = fmaxf(m, mo);
    float f1 = __expf(m - mn), f2 = __expf(mo - mn);
    s = s * f1 + so * f2;
    #pragma unroll
    for (int j = 0; j < 8; ++j) a[j] = a[j] * f1 + ao[j] * f2;
    m = mn;
  }

  float inv = (s > 0.f) ? 1.f / s : 0.f;
  if (g == 0) {
    uint4 ow;
    ow.x = (uint)f2b(a[0] * inv) | ((uint)f2b(a[1] * inv) << 16);
    ow.y = (uint)f2b(a[2] * inv) | ((uint)f2b(a[3] * inv) << 16);
    ow.z = (uint)f2b(a[4] * inv) | ((uint)f2b(a[5] * inv) << 16);
    ow.w = (uint)f2b(a[6] * inv) | ((uint)f2b(a[7] * inv) << 16);
    *reinterpret_cast<uint4*>(sav + (size_t)node * DM + sl * 8) = ow;
  }
}

// ---------------- LayerNorm (wave per node); optional bf16 second output ----------------
__global__ __launch_bounds__(256) void k_ln(
    const float* __restrict__ x, const float* __restrict__ g,
    const float* __restrict__ b, float* __restrict__ outf,
    ushort* __restrict__ outb, int n)
{
  int node = blockIdx.x * 4 + (threadIdx.x >> 6);
  int lane = threadIdx.x & 63;
  if (node >= n) return;
  size_t base = (size_t)node * DM + 2 * lane;
  float x0 = x[base], x1 = x[base + 1];
  float sum = x0 + x1;
  #pragma unroll
  for (int msk = 1; msk < 64; msk <<= 1) sum += __shfl_xor(sum, msk);
  float mu = sum * (1.f / DM);
  float d0 = x0 - mu, d1 = x1 - mu;
  float vs = d0 * d0 + d1 * d1;
  #pragma unroll
  for (int msk = 1; msk < 64; msk <<= 1) vs += __shfl_xor(vs, msk);
  float rstd = rsqrtf(vs * (1.f / DM) + LN_EPS);
  float y0 = d0 * rstd * g[2 * lane]     + b[2 * lane];
  float y1 = d1 * rstd * g[2 * lane + 1] + b[2 * lane + 1];
  outf[base]     = y0;
  outf[base + 1] = y1;
  if (outb) {
    ushort2 o; o.x = f2b(y0); o.y = f2b(y1);
    *reinterpret_cast<ushort2*>(outb + base) = o;
  }
}

extern "C" void kernel_launch(void* const* d_in, const int* in_sizes, int n_in,
                              void* d_out, int out_size, void* d_ws, size_t ws_size,
                              hipStream_t stream)
{
  const float* feat = (const float*)d_in[0];
  const int*   src  = (const int*)d_in[1];
  const int*   dst  = (const int*)d_in[2];
  const float* Wq   = (const float*)d_in[3];
  const float* Wk   = (const float*)d_in[4];
  const float* Wv   = (const float*)d_in[5];
  const float* Wo   = (const float*)d_in[6];
  const float* ln1g = (const float*)d_in[7];
  const float* ln1b = (const float*)d_in[8];
  const float* W1   = (const float*)d_in[9];
  const float* b1   = (const float*)d_in[10];
  const float* W2   = (const float*)d_in[11];
  const float* b2   = (const float*)d_in[12];
  const float* ln2g = (const float*)d_in[13];
  const float* ln2b = (const float*)d_in[14];
  float* out = (float*)d_out;

  const int N = in_sizes[0] / DM;
  const int E = in_sizes[1];
  const size_t NB = (size_t)N;

  char* wsb = (char*)d_ws;
  ushort* qkv_bf  = (ushort*)wsb;
  ushort* feat_bf = (ushort*)(wsb + NB * 768);
  ushort* sav_bf  = feat_bf;
  ushort* mid_bf  = (ushort*)wsb;
  float*  x1      = (float*)(wsb + NB * 1024);
  float*  h1      = (float*)(wsb + NB * 1024 + NB * 512);
  ushort* h1b     = (ushort*)(wsb + NB * 1024 + NB * 1024);
  ushort* wbf     = (ushort*)(wsb + NB * 1024 + NB * 1024 + NB * 256);
  ushort* wqkv_bf = wbf;
  ushort* wo_bf   = wbf + 49152;
  ushort* w1_bf   = wbf + 65536;
  ushort* w2_bf   = wbf + 131072;
  int* ib  = (int*)(wbf + 196608);
  int* deg = ib;
  int* cur = ib + N;
  int* off = ib + 2 * N;
  int* csr = ib + 3 * N + 1;

  hipMemsetAsync(deg, 0, 2 * (size_t)N * sizeof(int), stream);

  int nf = N * DM;
  k_cast<<<(nf / 4 + 255) / 256, 256, 0, stream>>>(feat, feat_bf, nf);
  k_castw<<<192, 256, 0, stream>>>(Wq, Wk, Wv, Wo, W1, W2, wbf);

  int eb = (E + 255) / 256;
  k_count<<<eb, 256, 0, stream>>>(dst, deg, E);
  k_scan<<<1, 1024, 0, stream>>>(deg, off, N);
  k_scatter<<<eb, 256, 0, stream>>>(src, dst, off, cur, csr, E);

  const int gy = (N + BM - 1) / BM;
  k_mm<0, false, true><<<dim3(3, gy), 256, 0, stream>>>(
      feat_bf, wqkv_bf, nullptr, nullptr, nullptr, qkv_bf, N, 384, DM);

  int nb4 = (N + 3) / 4;
  k_attn<<<nb4, 256, 0, stream>>>(qkv_bf, off, csr, sav_bf, N);

  k_mm<4, true, false><<<dim3(1, gy), 256, 0, stream>>>(
      sav_bf, wo_bf, nullptr, feat, x1, nullptr, N, DM, DM);
  k_ln<<<nb4, 256, 0, stream>>>(x1, ln1g, ln1b, h1, h1b, N);

  k_mm<3, false, true><<<dim3(4, gy), 256, 0, stream>>>(
      h1b, w1_bf, b1, nullptr, nullptr, mid_bf, N, DFF, DM);
  k_mm<5, true, false><<<dim3(1, gy), 256, 0, stream>>>(
      mid_bf, w2_bf, b2, h1, x1, nullptr, N, DM, DFF);

  k_ln<<<nb4, 256, 0, stream>>>(x1, ln2g, ln2b, out, nullptr, N);
}

// Round 4
// 236.922 us; speedup vs baseline: 2.4719x; 1.2331x over previous
//
#include <hip/hip_runtime.h>

#define DM 128
#define DFF 512
#define CLAMP_V 5.0f
#define LN_EPS 1e-5f

typedef __attribute__((ext_vector_type(8))) short bf16x8;
typedef __attribute__((ext_vector_type(4))) float f32x4;

__device__ __forceinline__ float b2f(ushort u) {
  union { uint u; float f; } x; x.u = ((uint)u) << 16; return x.f;
}
__device__ __forceinline__ ushort f2b(float f) {
  union { float f; uint u; } x; x.f = f;
  uint r = x.u + 0x7FFFu + ((x.u >> 16) & 1u);
  return (ushort)(r >> 16);
}
__device__ __forceinline__ void unpack8(uint4 w, float* o) {
  o[0] = b2f((ushort)w.x); o[1] = b2f((ushort)(w.x >> 16));
  o[2] = b2f((ushort)w.y); o[3] = b2f((ushort)(w.y >> 16));
  o[4] = b2f((ushort)w.z); o[5] = b2f((ushort)(w.z >> 16));
  o[6] = b2f((ushort)w.w); o[7] = b2f((ushort)(w.w >> 16));
}

// ---------------- casts ----------------
__global__ void k_cast(const float* __restrict__ s, ushort* __restrict__ d, int n) {
  int i4 = (blockIdx.x * blockDim.x + threadIdx.x) * 4;
  if (i4 + 3 < n) {
    float4 v = *reinterpret_cast<const float4*>(s + i4);
    ushort4 o; o.x = f2b(v.x); o.y = f2b(v.y); o.z = f2b(v.z); o.w = f2b(v.w);
    *reinterpret_cast<ushort4*>(d + i4) = o;
  } else {
    for (; i4 < n; ++i4) d[i4] = f2b(s[i4]);
  }
}

__global__ void k_castw(const float* __restrict__ wq, const float* __restrict__ wk,
                        const float* __restrict__ wv, const float* __restrict__ wo,
                        const float* __restrict__ w1, const float* __restrict__ w2,
                        ushort* __restrict__ d) {
  int i4 = (blockIdx.x * blockDim.x + threadIdx.x) * 4;
  if (i4 >= 196608) return;
  const float* s; int o;
  if      (i4 < 16384)  { s = wq; o = i4; }
  else if (i4 < 32768)  { s = wk; o = i4 - 16384; }
  else if (i4 < 49152)  { s = wv; o = i4 - 32768; }
  else if (i4 < 65536)  { s = wo; o = i4 - 49152; }
  else if (i4 < 131072) { s = w1; o = i4 - 65536; }
  else                  { s = w2; o = i4 - 131072; }
  float4 v = *reinterpret_cast<const float4*>(s + o);
  ushort4 u; u.x = f2b(v.x); u.y = f2b(v.y); u.z = f2b(v.z); u.w = f2b(v.w);
  *reinterpret_cast<ushort4*>(d + i4) = u;
}

// ---------------- CSR build ----------------
__global__ void k_count(const int* __restrict__ dst, int* __restrict__ deg, int E) {
  int e = blockIdx.x * blockDim.x + threadIdx.x;
  if (e < E) atomicAdd(&deg[dst[e]], 1);
}

// hierarchical exclusive scan: 1024 elements per block (256 thr x int4)
#define SC_EPB 1024

__global__ __launch_bounds__(256) void k_scan1(const int* __restrict__ deg,
                                               int* __restrict__ off,
                                               int* __restrict__ bsum, int n) {
  __shared__ int sh[256];
  const int t = threadIdx.x;
  int base = blockIdx.x * SC_EPB + t * 4;
  int4 v = {0, 0, 0, 0};
  if (base + 3 < n) {
    v = *reinterpret_cast<const int4*>(deg + base);
  } else {
    if (base     < n) v.x = deg[base];
    if (base + 1 < n) v.y = deg[base + 1];
    if (base + 2 < n) v.z = deg[base + 2];
    if (base + 3 < n) v.w = deg[base + 3];
  }
  int s = v.x + v.y + v.z + v.w;
  sh[t] = s;
  __syncthreads();
  #pragma unroll
  for (int d = 1; d < 256; d <<= 1) {
    int x = 0;
    if (t >= d) x = sh[t - d];
    __syncthreads();
    sh[t] += x;
    __syncthreads();
  }
  int ex = sh[t] - s;   // exclusive prefix of this thread's 4-chunk
  if (base + 3 < n) {
    int4 o; o.x = ex; o.y = ex + v.x; o.z = ex + v.x + v.y; o.w = ex + v.x + v.y + v.z;
    *reinterpret_cast<int4*>(off + base) = o;
  } else {
    if (base     < n) off[base]     = ex;
    if (base + 1 < n) off[base + 1] = ex + v.x;
    if (base + 2 < n) off[base + 2] = ex + v.x + v.y;
    if (base + 3 < n) off[base + 3] = ex + v.x + v.y + v.z;
  }
  if (t == 255) bsum[blockIdx.x] = sh[255];
}

__global__ __launch_bounds__(256) void k_scan2(int* __restrict__ bsum, int nb) {
  __shared__ int sh[256];
  const int t = threadIdx.x;
  int v = (t < nb) ? bsum[t] : 0;
  sh[t] = v;
  __syncthreads();
  #pragma unroll
  for (int d = 1; d < 256; d <<= 1) {
    int x = 0;
    if (t >= d) x = sh[t - d];
    __syncthreads();
    sh[t] += x;
    __syncthreads();
  }
  if (t < nb) bsum[t] = sh[t] - v;   // exclusive block offsets
}

__global__ __launch_bounds__(256) void k_scan3(int* __restrict__ off,
                                               const int* __restrict__ bsum,
                                               int n, int E) {
  int add = bsum[blockIdx.x];
  int base = blockIdx.x * SC_EPB + threadIdx.x * 4;
  if (base + 3 < n) {
    int4 v = *reinterpret_cast<int4*>(off + base);
    v.x += add; v.y += add; v.z += add; v.w += add;
    *reinterpret_cast<int4*>(off + base) = v;
  } else {
    if (base     < n) off[base]     += add;
    if (base + 1 < n) off[base + 1] += add;
    if (base + 2 < n) off[base + 2] += add;
  }
  if (blockIdx.x == 0 && threadIdx.x == 0) off[n] = E;
}

__global__ void k_scatter(const int* __restrict__ src, const int* __restrict__ dst,
                          const int* __restrict__ off, int* __restrict__ cur,
                          int* __restrict__ csr, int E) {
  int e = blockIdx.x * blockDim.x + threadIdx.x;
  if (e < E) {
    int d = dst[e];
    int p = off[d] + atomicAdd(&cur[d], 1);
    csr[p] = src[e];
  }
}

// ---------------- bf16 MFMA GEMM ----------------
#define BM 128
#define BN 128
#define BK 64

template<int FLAGS, bool OUTF, bool OUTB>
__global__ __launch_bounds__(256, 3) void k_mm(
    const ushort* __restrict__ A, const ushort* __restrict__ W,
    const float* __restrict__ bias, const float* __restrict__ res,
    float* __restrict__ Cf, ushort* __restrict__ Cb,
    int M, int NO, int K)
{
  __shared__ ushort As[BM * BK];
  __shared__ ushort Ws[BN * BK];
  const int tid = threadIdx.x;
  const int wv = tid >> 6, ln = tid & 63;
  const int bm = blockIdx.y * BM, bn = blockIdx.x * BN;
  const int wrow = (wv >> 1) * 64, wcol = (wv & 1) * 64;

  f32x4 acc[4][4] = {};
  const int o_base = wv * 1024 + ln * 16;

  for (int k0 = 0; k0 < K; k0 += BK) {
    #pragma unroll
    for (int is = 0; is < 4; ++is) {
      int o = is * 4096 + o_base;
      int row = o >> 7;
      int c = ((o >> 4) & 7) ^ (row & 7);
      int gm = bm + row; if (gm >= M) gm = M - 1;
      const ushort* srcA = A + (size_t)gm * K + k0 + c * 8;
      __builtin_amdgcn_global_load_lds(
          (const __attribute__((address_space(1))) void*)srcA,
          (__attribute__((address_space(3))) void*)((char*)As + is * 4096 + wv * 1024),
          16, 0, 0);
      int gn = bn + row;
      const ushort* srcW = W + (size_t)gn * K + k0 + c * 8;
      __builtin_amdgcn_global_load_lds(
          (const __attribute__((address_space(1))) void*)srcW,
          (__attribute__((address_space(3))) void*)((char*)Ws + is * 4096 + wv * 1024),
          16, 0, 0);
    }
    __syncthreads();

    const char* AsB = (const char*)As;
    const char* WsB = (const char*)Ws;
    #pragma unroll
    for (int kk = 0; kk < 2; ++kk) {
      bf16x8 af[4], bf[4];
      #pragma unroll
      for (int m = 0; m < 4; ++m) {
        int r = wrow + m * 16 + (ln & 15);
        int c = kk * 4 + (ln >> 4);
        af[m] = *reinterpret_cast<const bf16x8*>(AsB + r * 128 + ((c ^ (r & 7)) << 4));
      }
      #pragma unroll
      for (int n = 0; n < 4; ++n) {
        int r = wcol + n * 16 + (ln & 15);
        int c = kk * 4 + (ln >> 4);
        bf[n] = *reinterpret_cast<const bf16x8*>(WsB + r * 128 + ((c ^ (r & 7)) << 4));
      }
      #pragma unroll
      for (int m = 0; m < 4; ++m)
        #pragma unroll
        for (int n = 0; n < 4; ++n)
          acc[m][n] = __builtin_amdgcn_mfma_f32_16x16x32_bf16(af[m], bf[n], acc[m][n], 0, 0, 0);
    }
    __syncthreads();
  }

  #pragma unroll
  for (int m = 0; m < 4; ++m) {
    int gr0 = bm + wrow + m * 16 + (ln >> 4) * 4;
    #pragma unroll
    for (int n = 0; n < 4; ++n) {
      int gc = bn + wcol + n * 16 + (ln & 15);
      float bsv = (FLAGS & 1) ? bias[gc] : 0.f;
      #pragma unroll
      for (int r = 0; r < 4; ++r) {
        int gr = gr0 + r;
        if (gr >= M) continue;
        float v = acc[m][n][r] + bsv;
        if (FLAGS & 2) v = fmaxf(v, 0.f);
        if (FLAGS & 4) v += res[(size_t)gr * NO + gc];
        if (OUTF) Cf[(size_t)gr * NO + gc] = v;
        if (OUTB) Cb[(size_t)gr * NO + gc] = f2b(v);
      }
    }
  }
}

// ---------------- per-node edge-softmax attention, 4 edges in flight per wave ----
__global__ __launch_bounds__(256) void k_attn(
    const ushort* __restrict__ qkv, const int* __restrict__ off,
    const int* __restrict__ csr, ushort* __restrict__ sav, int n)
{
  int node = blockIdx.x * 4 + (threadIdx.x >> 6);
  int lane = threadIdx.x & 63;
  if (node >= n) return;
  const int g = lane >> 4, sl = lane & 15;

  uint4 qw = *reinterpret_cast<const uint4*>(qkv + (size_t)node * 384 + sl * 8);
  float qv[8]; unpack8(qw, qv);

  int b = off[node], e = off[node + 1];
  float m = -1e30f, s = 0.f;
  float a[8] = {};
  int nIt = (e - b + 3) >> 2;
  int idx = b + g;
  int sn = (b < e) ? csr[min(idx, e - 1)] : 0;

  for (int i = 0; i < nIt; ++i) {
    bool act = idx < e;
    const ushort* kr = qkv + (size_t)sn * 384 + 128 + sl * 8;
    uint4 kw = *reinterpret_cast<const uint4*>(kr);
    uint4 vw = *reinterpret_cast<const uint4*>(kr + 128);
    int idxn = idx + 4;
    if (i + 1 < nIt) sn = csr[min(idxn, e - 1)];
    idx = idxn;

    float kv[8]; unpack8(kw, kv);
    float p = 0.f;
    #pragma unroll
    for (int j = 0; j < 8; ++j) p = fmaf(qv[j], kv[j], p);
    p += __shfl_xor(p, 1);
    float u = fminf(fmaxf(p * 0.25f, -CLAMP_V), CLAMP_V);
    if (act) {
      float mn = fmaxf(m, u);
      float f = __expf(m - mn);
      float w = __expf(u - mn);
      s = s * f + w;
      float vv[8]; unpack8(vw, vv);
      #pragma unroll
      for (int j = 0; j < 8; ++j) a[j] = a[j] * f + w * vv[j];
      m = mn;
    }
  }

  #pragma unroll
  for (int msk = 16; msk <= 32; msk <<= 1) {
    float mo = __shfl_xor(m, msk);
    float so = __shfl_xor(s, msk);
    float ao[8];
    #pragma unroll
    for (int j = 0; j < 8; ++j) ao[j] = __shfl_xor(a[j], msk);
    float mn = fmaxf(m, mo);
    float f1 = __expf(m - mn), f2 = __expf(mo - mn);
    s = s * f1 + so * f2;
    #pragma unroll
    for (int j = 0; j < 8; ++j) a[j] = a[j] * f1 + ao[j] * f2;
    m = mn;
  }

  float inv = (s > 0.f) ? 1.f / s : 0.f;
  if (g == 0) {
    uint4 ow;
    ow.x = (uint)f2b(a[0] * inv) | ((uint)f2b(a[1] * inv) << 16);
    ow.y = (uint)f2b(a[2] * inv) | ((uint)f2b(a[3] * inv) << 16);
    ow.z = (uint)f2b(a[4] * inv) | ((uint)f2b(a[5] * inv) << 16);
    ow.w = (uint)f2b(a[6] * inv) | ((uint)f2b(a[7] * inv) << 16);
    *reinterpret_cast<uint4*>(sav + (size_t)node * DM + sl * 8) = ow;
  }
}

// ---------------- LayerNorm ----------------
__global__ __launch_bounds__(256) void k_ln(
    const float* __restrict__ x, const float* __restrict__ g,
    const float* __restrict__ b, float* __restrict__ outf,
    ushort* __restrict__ outb, int n)
{
  int node = blockIdx.x * 4 + (threadIdx.x >> 6);
  int lane = threadIdx.x & 63;
  if (node >= n) return;
  size_t base = (size_t)node * DM + 2 * lane;
  float x0 = x[base], x1 = x[base + 1];
  float sum = x0 + x1;
  #pragma unroll
  for (int msk = 1; msk < 64; msk <<= 1) sum += __shfl_xor(sum, msk);
  float mu = sum * (1.f / DM);
  float d0 = x0 - mu, d1 = x1 - mu;
  float vs = d0 * d0 + d1 * d1;
  #pragma unroll
  for (int msk = 1; msk < 64; msk <<= 1) vs += __shfl_xor(vs, msk);
  float rstd = rsqrtf(vs * (1.f / DM) + LN_EPS);
  float y0 = d0 * rstd * g[2 * lane]     + b[2 * lane];
  float y1 = d1 * rstd * g[2 * lane + 1] + b[2 * lane + 1];
  outf[base]     = y0;
  outf[base + 1] = y1;
  if (outb) {
    ushort2 o; o.x = f2b(y0); o.y = f2b(y1);
    *reinterpret_cast<ushort2*>(outb + base) = o;
  }
}

extern "C" void kernel_launch(void* const* d_in, const int* in_sizes, int n_in,
                              void* d_out, int out_size, void* d_ws, size_t ws_size,
                              hipStream_t stream)
{
  const float* feat = (const float*)d_in[0];
  const int*   src  = (const int*)d_in[1];
  const int*   dst  = (const int*)d_in[2];
  const float* Wq   = (const float*)d_in[3];
  const float* Wk   = (const float*)d_in[4];
  const float* Wv   = (const float*)d_in[5];
  const float* Wo   = (const float*)d_in[6];
  const float* ln1g = (const float*)d_in[7];
  const float* ln1b = (const float*)d_in[8];
  const float* W1   = (const float*)d_in[9];
  const float* b1   = (const float*)d_in[10];
  const float* W2   = (const float*)d_in[11];
  const float* b2   = (const float*)d_in[12];
  const float* ln2g = (const float*)d_in[13];
  const float* ln2b = (const float*)d_in[14];
  float* out = (float*)d_out;

  const int N = in_sizes[0] / DM;
  const int E = in_sizes[1];
  const size_t NB = (size_t)N;

  char* wsb = (char*)d_ws;
  ushort* qkv_bf  = (ushort*)wsb;
  ushort* feat_bf = (ushort*)(wsb + NB * 768);
  ushort* sav_bf  = feat_bf;
  ushort* mid_bf  = (ushort*)wsb;
  float*  x1      = (float*)(wsb + NB * 1024);
  float*  h1      = (float*)(wsb + NB * 1024 + NB * 512);
  ushort* h1b     = (ushort*)(wsb + NB * 1024 + NB * 1024);
  ushort* wbf     = (ushort*)(wsb + NB * 1024 + NB * 1024 + NB * 256);
  ushort* wqkv_bf = wbf;
  ushort* wo_bf   = wbf + 49152;
  ushort* w1_bf   = wbf + 65536;
  ushort* w2_bf   = wbf + 131072;
  int* ib  = (int*)(wbf + 196608);
  int* deg = ib;
  int* cur = ib + N;
  int* off = ib + 2 * N;
  int* csr = ib + 3 * N + 1;
  int* bsum = csr + E;

  hipMemsetAsync(deg, 0, 2 * (size_t)N * sizeof(int), stream);

  int nf = N * DM;
  k_cast<<<(nf / 4 + 255) / 256, 256, 0, stream>>>(feat, feat_bf, nf);
  k_castw<<<192, 256, 0, stream>>>(Wq, Wk, Wv, Wo, W1, W2, wbf);

  int eb = (E + 255) / 256;
  int nbk = (N + SC_EPB - 1) / SC_EPB;
  k_count<<<eb, 256, 0, stream>>>(dst, deg, E);
  k_scan1<<<nbk, 256, 0, stream>>>(deg, off, bsum, N);
  k_scan2<<<1, 256, 0, stream>>>(bsum, nbk);
  k_scan3<<<nbk, 256, 0, stream>>>(off, bsum, N, E);
  k_scatter<<<eb, 256, 0, stream>>>(src, dst, off, cur, csr, E);

  const int gy = (N + BM - 1) / BM;
  k_mm<0, false, true><<<dim3(3, gy), 256, 0, stream>>>(
      feat_bf, wqkv_bf, nullptr, nullptr, nullptr, qkv_bf, N, 384, DM);

  int nb4 = (N + 3) / 4;
  k_attn<<<nb4, 256, 0, stream>>>(qkv_bf, off, csr, sav_bf, N);

  k_mm<4, true, false><<<dim3(1, gy), 256, 0, stream>>>(
      sav_bf, wo_bf, nullptr, feat, x1, nullptr, N, DM, DM);
  k_ln<<<nb4, 256, 0, stream>>>(x1, ln1g, ln1b, h1, h1b, N);

  k_mm<3, false, true><<<dim3(4, gy), 256, 0, stream>>>(
      h1b, w1_bf, b1, nullptr, nullptr, mid_bf, N, DFF, DM);
  k_mm<5, true, false><<<dim3(1, gy), 256, 0, stream>>>(
      mid_bf, w2_bf, b2, h1, x1, nullptr, N, DM, DFF);

  k_ln<<<nb4, 256, 0, stream>>>(x1, ln2g, ln2b, out, nullptr, N);
}